// Round 6
// baseline (5896.002 us; speedup 1.0000x reference)
//
#include <hip/hip_runtime.h>
#include <math.h>

// Problem constants
#define N_USERS 4096
#define KNB 32
#define DIM 768
#define NHEAD 4
#define DHEAD 192

// Pipeline shape — round-2-proven protocol, only the interleave factors changed
#define NG_M 7               // matvec step-interleave groups (was 8)
#define NG_A 32              // attention step-interleave groups (was 16)
#define NMV_WG 72            // WGs per matvec group (72*32 = 2304 rows: out|K|V)
#define NMVTOT (NG_M * NMV_WG)          // 504
#define NWG (NMVTOT + NG_A * NHEAD)     // 632  (<= 640 proven co-resident in round 2)

// ---- workspace layout (bytes) — identical to round 2 ----
static constexpr size_t OFF_CALL   = 0;            // [4096][2304] f32 : Qall | K0 | V0
static constexpr size_t OFF_KNEW   = 37748736;     // [4096][768]
static constexpr size_t OFF_VNEW   = 50331648;     // [4096][768]
static constexpr size_t OFF_OBUF   = 62914560;     // [4096][768]
static constexpr size_t OFF_WOK    = 75497472;     // [768][768]  Wk@Wout
static constexpr size_t OFF_WOV    = 77856768;     // [768][768]  Wv@Wout
static constexpr size_t OFF_BOKV   = 80216064;     // [1536]
static constexpr size_t OFF_OFLAG  = 80222208;     // [4096] int, stride 32 ints (128B)
static constexpr size_t OFF_DONEKV = 80746496;     // [4096][4] int, stride 32 ints
static constexpr size_t WS_NEEDED  = 82843648;     // ~79 MiB

__device__ __forceinline__ float dot4(float4 a, float4 b) {
  return fmaf(a.x, b.x, fmaf(a.y, b.y, fmaf(a.z, b.z, a.w * b.w)));
}

// =====================  C[M x Ncols] = A[M x K] * B[Ncols x K]^T + bias[col]  =====================
__global__ __launch_bounds__(256) void gemm_nt_bias(
    const float* __restrict__ A, const float* __restrict__ B,
    const float* __restrict__ bias, float* __restrict__ C,
    int Kdim, int Ncols)
{
  __shared__ float As[16][68];
  __shared__ float Bs[16][68];
  const int t  = threadIdx.x;
  const int tm = t & 15, tn = t >> 4;
  const int row0 = blockIdx.y * 64;
  const int col0 = blockIdx.x * 64;
  const int lr = t >> 2, lk = (t & 3) << 2;
  float acc[4][4] = {};
  for (int k0 = 0; k0 < Kdim; k0 += 16) {
    float4 av = *(const float4*)(A + (size_t)(row0 + lr) * Kdim + k0 + lk);
    float4 bv = *(const float4*)(B + (size_t)(col0 + lr) * Kdim + k0 + lk);
    As[lk + 0][lr] = av.x; As[lk + 1][lr] = av.y; As[lk + 2][lr] = av.z; As[lk + 3][lr] = av.w;
    Bs[lk + 0][lr] = bv.x; Bs[lk + 1][lr] = bv.y; Bs[lk + 2][lr] = bv.z; Bs[lk + 3][lr] = bv.w;
    __syncthreads();
#pragma unroll
    for (int k = 0; k < 16; ++k) {
      float4 a4 = *(const float4*)&As[k][tm << 2];
      float4 b4 = *(const float4*)&Bs[k][tn << 2];
      float aa[4] = {a4.x, a4.y, a4.z, a4.w};
      float bb[4] = {b4.x, b4.y, b4.z, b4.w};
#pragma unroll
      for (int x = 0; x < 4; ++x)
#pragma unroll
        for (int y = 0; y < 4; ++y) acc[x][y] = fmaf(aa[x], bb[y], acc[x][y]);
    }
    __syncthreads();
  }
  float4 bi = *(const float4*)(bias + col0 + (tn << 2));
#pragma unroll
  for (int x = 0; x < 4; ++x) {
    float4 o = make_float4(acc[x][0] + bi.x, acc[x][1] + bi.y, acc[x][2] + bi.z, acc[x][3] + bi.w);
    *(float4*)(C + (size_t)(row0 + (tm << 2) + x) * Ncols + col0 + (tn << 2)) = o;
  }
}

// =====================  C[M x Ncols] = A[M x K] * B[K x Ncols]  (no bias)  =====================
__global__ __launch_bounds__(256) void gemm_nn(
    const float* __restrict__ A, const float* __restrict__ B, float* __restrict__ C,
    int Kdim, int Ncols)
{
  __shared__ float As[16][68];
  __shared__ float Bs[16][68];
  const int t  = threadIdx.x;
  const int tm = t & 15, tn = t >> 4;
  const int row0 = blockIdx.y * 64;
  const int col0 = blockIdx.x * 64;
  const int lr = t >> 2, lk = (t & 3) << 2;
  const int ek = t >> 4, dc = (t & 15) << 2;
  float acc[4][4] = {};
  for (int k0 = 0; k0 < Kdim; k0 += 16) {
    float4 av = *(const float4*)(A + (size_t)(row0 + lr) * Kdim + k0 + lk);
    As[lk + 0][lr] = av.x; As[lk + 1][lr] = av.y; As[lk + 2][lr] = av.z; As[lk + 3][lr] = av.w;
    float4 bv = *(const float4*)(B + (size_t)(k0 + ek) * Ncols + col0 + dc);
    *(float4*)&Bs[ek][dc] = bv;
    __syncthreads();
#pragma unroll
    for (int k = 0; k < 16; ++k) {
      float4 a4 = *(const float4*)&As[k][tm << 2];
      float4 b4 = *(const float4*)&Bs[k][tn << 2];
      float aa[4] = {a4.x, a4.y, a4.z, a4.w};
      float bb[4] = {b4.x, b4.y, b4.z, b4.w};
#pragma unroll
      for (int x = 0; x < 4; ++x)
#pragma unroll
        for (int y = 0; y < 4; ++y) acc[x][y] = fmaf(aa[x], bb[y], acc[x][y]);
    }
    __syncthreads();
  }
#pragma unroll
  for (int x = 0; x < 4; ++x) {
    float4 o = make_float4(acc[x][0], acc[x][1], acc[x][2], acc[x][3]);
    *(float4*)(C + (size_t)(row0 + (tm << 2) + x) * Ncols + col0 + (tn << 2)) = o;
  }
}

// bokv[j] = Wk[j,:]·bout + bk[j];  bokv[768+j] = Wv[j,:]·bout + bv[j]
__global__ __launch_bounds__(256) void fuse_bias(
    const float* __restrict__ in_w, const float* __restrict__ in_b,
    const float* __restrict__ bout, float* __restrict__ bokv)
{
  int jj = blockIdx.x * 256 + threadIdx.x;
  if (jj >= 1536) return;
  const float* wrow = in_w + (size_t)(768 + jj) * 768;
  float s = 0.f;
  for (int e = 0; e < 768; e += 4) {
    float4 w4 = *(const float4*)(wrow + e);
    float4 b4 = *(const float4*)(bout + e);
    s += dot4(w4, b4);
  }
  bokv[jj] = s + in_b[768 + jj];
}

// =====================  persistent out-of-order dataflow kernel (round-2 protocol)  =====================
__global__ __launch_bounds__(256, 4) void multiattn_main(
    const int* __restrict__ nbr,
    const float* __restrict__ Call,
    float* __restrict__ Knew, float* __restrict__ Vnew,
    float* __restrict__ obuf,
    const float* __restrict__ Wout, const float* __restrict__ Wok, const float* __restrict__ Wov,
    const float* __restrict__ bout, const float* __restrict__ bokv,
    int* __restrict__ oflag, int* __restrict__ doneKV,
    float* __restrict__ outF)
{
  const int w = blockIdx.x;
  const int t = threadIdx.x;

  if (w < NMVTOT) {
    // ---------------- matvec army: NG_M groups x 72 WGs; 32 rows/WG, 8 lanes per dot ----------------
    const int g = w / NMV_WG;
    const int j = w - g * NMV_WG;
    __shared__ float o_lds[800];                 // 8 chunks of 96, stride 100
    const int gg = t >> 3, l = t & 7;
    const int seg = (j * 32) / 768;              // 0: out-proj, 1: Wok, 2: Wov
    const int rowInSeg = j * 32 + gg - seg * 768;
    const int headOfWG = (j * 32 - seg * 768) / DHEAD;   // uniform per WG (segs 1,2)
    const float* wsrc = (seg == 0) ? Wout : (seg == 1) ? Wok : Wov;
    const float* wrow = wsrc + (size_t)rowInSeg * 768 + l * 96;
    float4 wreg[24];
#pragma unroll
    for (int q = 0; q < 24; ++q) wreg[q] = *(const float4*)(wrow + 4 * q);
    const float biasv = (seg == 0) ? bout[rowInSeg] : bokv[(seg - 1) * 768 + rowInSeg];
    float* dest = (seg == 0) ? outF : (seg == 1) ? Knew : Vnew;

    for (int i = g; i < N_USERS; i += NG_M) {
      if (t == 0) {
        const int* fp = oflag + ((size_t)i << 5);
        while (__hip_atomic_load(fp, __ATOMIC_RELAXED, __HIP_MEMORY_SCOPE_AGENT) < NHEAD)
          __builtin_amdgcn_s_sleep(8);
        (void)__hip_atomic_load(fp, __ATOMIC_ACQUIRE, __HIP_MEMORY_SCOPE_AGENT);
      }
      __syncthreads();
      if (t < 192) {
        int d0 = t << 2;
        int ll = t / 24;
        int m  = d0 - ll * 96;
        *(float4*)&o_lds[ll * 100 + m] = *(const float4*)(obuf + (size_t)i * 768 + d0);
      }
      __syncthreads();
      float acc = 0.f;
      const float4* op = (const float4*)&o_lds[l * 100];
#pragma unroll
      for (int q = 0; q < 24; ++q) acc += dot4(wreg[q], op[q]);
      acc += __shfl_xor(acc, 1);
      acc += __shfl_xor(acc, 2);
      acc += __shfl_xor(acc, 4);
      if (l == 0) dest[(size_t)i * 768 + rowInSeg] = acc + biasv;
      __syncthreads();
      if (t == 0 && seg > 0)
        __hip_atomic_fetch_add(doneKV + (((size_t)i * NHEAD + headOfWG) << 5), 1,
                               __ATOMIC_RELEASE, __HIP_MEMORY_SCOPE_AGENT);
    }
  } else {
    // ---------------- attention: NG_A groups x 4 heads ----------------
    const int a = w - NMVTOT;
    const int g = a >> 2;
    const int h = a & 3;
    __shared__ int   idxb[2][KNB];
    __shared__ float sc[KNB], aw[KNB];
    __shared__ float opart[KNB][200];
    const int kp = t >> 3, l = t & 7;
    const int col = h * DHEAD + l * 24;
    if (t < KNB) idxb[0][t] = nbr[g * KNB + t];
    __syncthreads();

    for (int i = g; i < N_USERS; i += NG_A) {
      const int par = (i >> 5) & 1;              // NG_A=32: alternates per iteration
      const int r = idxb[par][kp];

      // q load hoisted above the dependency wait (overlaps spin latency)
      const float* qp = Call + (size_t)i * 2304 + col;
      float4 q4[6];
#pragma unroll
      for (int jj = 0; jj < 6; ++jj) q4[jj] = *(const float4*)(qp + 4 * jj);

      if (r < i) {   // all 8 lanes of this kp spin (coalesced same-address loads)
        const int* fp = doneKV + (((size_t)r * NHEAD + h) << 5);
        while (__hip_atomic_load(fp, __ATOMIC_RELAXED, __HIP_MEMORY_SCOPE_AGENT) < 12)
          __builtin_amdgcn_s_sleep(2);
        (void)__hip_atomic_load(fp, __ATOMIC_ACQUIRE, __HIP_MEMORY_SCOPE_AGENT);
      }
      const float* kptr = (r < i) ? (Knew + (size_t)r * 768 + col)
                                  : (Call + (size_t)r * 2304 + 768 + col);
      const float* vptr = (r < i) ? (Vnew + (size_t)r * 768 + col)
                                  : (Call + (size_t)r * 2304 + 1536 + col);
      float4 k4[6], v4[6];
#pragma unroll
      for (int jj = 0; jj < 6; ++jj) k4[jj] = *(const float4*)(kptr + 4 * jj);
#pragma unroll
      for (int jj = 0; jj < 6; ++jj) v4[jj] = *(const float4*)(vptr + 4 * jj);
      float p = 0.f;
#pragma unroll
      for (int jj = 0; jj < 6; ++jj) p += dot4(q4[jj], k4[jj]);
      p += __shfl_xor(p, 1); p += __shfl_xor(p, 2); p += __shfl_xor(p, 4);
      if (l == 0) sc[kp] = p * 0.07216878364870322f;   // 1/sqrt(192)
      int rn = 0;
      const bool pf = (t < KNB) && (i + NG_A < N_USERS);
      if (pf) rn = nbr[(size_t)(i + NG_A) * KNB + t];
      __syncthreads();
      if (t < KNB) {
        float s = sc[t];
        float mx = s;
#pragma unroll
        for (int msk = 16; msk >= 1; msk >>= 1) mx = fmaxf(mx, __shfl_xor(mx, msk));
        float e = expf(s - mx);
        float sm = e;
#pragma unroll
        for (int msk = 16; msk >= 1; msk >>= 1) sm += __shfl_xor(sm, msk);
        aw[t] = e / sm;
      }
      if (pf) idxb[1 - par][t] = rn;
      __syncthreads();
      const float av = aw[kp];
      float* od = &opart[kp][l * 24];
#pragma unroll
      for (int jj = 0; jj < 6; ++jj)
        *(float4*)(od + 4 * jj) = make_float4(av * v4[jj].x, av * v4[jj].y, av * v4[jj].z, av * v4[jj].w);
      __syncthreads();
      if (t < DHEAD) {
        float o = 0.f;
#pragma unroll
        for (int kk = 0; kk < KNB; ++kk) o += opart[kk][t];
        obuf[(size_t)i * 768 + h * DHEAD + t] = o;
      }
      __syncthreads();
      if (t == 0)
        __hip_atomic_fetch_add(oflag + ((size_t)i << 5), 1,
                               __ATOMIC_RELEASE, __HIP_MEMORY_SCOPE_AGENT);
    }
  }
}

extern "C" void kernel_launch(void* const* d_in, const int* in_sizes, int n_in,
                              void* d_out, int out_size, void* d_ws, size_t ws_size,
                              hipStream_t stream)
{
  (void)in_sizes; (void)n_in; (void)out_size; (void)ws_size;
  const int*   nbr   = (const int*)d_in[0];
  const float* feat  = (const float*)d_in[1];
  const float* in_w  = (const float*)d_in[2];
  const float* in_b  = (const float*)d_in[3];
  const float* out_w = (const float*)d_in[4];
  const float* out_b = (const float*)d_in[5];
  float* outF = (float*)d_out;
  char*  ws   = (char*)d_ws;

  float* Call = (float*)(ws + OFF_CALL);
  float* Knew = (float*)(ws + OFF_KNEW);
  float* Vnew = (float*)(ws + OFF_VNEW);
  float* obuf = (float*)(ws + OFF_OBUF);
  float* Wok  = (float*)(ws + OFF_WOK);
  float* Wov  = (float*)(ws + OFF_WOV);
  float* bokv = (float*)(ws + OFF_BOKV);
  int* oflag  = (int*)(ws + OFF_OFLAG);
  int* doneKV = (int*)(ws + OFF_DONEKV);

  // zero the flag region (ws is poisoned 0xAA before every call)
  hipMemsetAsync(ws + OFF_OFLAG, 0, WS_NEEDED - OFF_OFLAG, stream);

  // Qall | K0 | V0 = F0 @ [Wq;Wk;Wv]^T + b   -> Call [4096 x 2304]
  gemm_nt_bias<<<dim3(36, 64), 256, 0, stream>>>(feat, in_w, in_b, Call, 768, 2304);
  // Wok = Wk @ Wout, Wov = Wv @ Wout
  gemm_nn<<<dim3(12, 12), 256, 0, stream>>>(in_w + (size_t)768 * 768,  out_w, Wok, 768, 768);
  gemm_nn<<<dim3(12, 12), 256, 0, stream>>>(in_w + (size_t)1536 * 768, out_w, Wov, 768, 768);
  fuse_bias<<<6, 256, 0, stream>>>(in_w, in_b, out_b, bokv);

  multiattn_main<<<NWG, 256, 0, stream>>>(nbr, Call, Knew, Vnew, obuf,
      out_w, Wok, Wov, out_b, bokv, oflag, doneKV, outF);
}

// Round 7
// 4466.767 us; speedup vs baseline: 1.3200x; 1.3200x over previous
//
#include <hip/hip_runtime.h>
#include <math.h>

// Problem constants
#define N_USERS 4096
#define KNB 32
#define DIM 768
#define NHEAD 4
#define DHEAD 192

// Pipeline shape — static residues (proven protocol family; NO dynamic tickets)
#define NG_V 21              // V-army step-interleave groups
#define NSLICE_V 24          // 24 slices x 32 rows = 768 V rows
#define NMVTOT (NG_V * NSLICE_V)        // 504
#define NG_A 128             // attention groups, one WG per step (all 4 heads)
#define NWG (NMVTOT + NG_A)             // 632 == round-6 proven co-resident count

// ---- workspace layout (bytes) ----
static constexpr size_t OFF_CALL  = 0;           // [4096][2304] f32 : Qall | K0 | V0
static constexpr size_t OFF_VNEW  = 37748736;    // [4096][768]
static constexpr size_t OFF_OBUF  = 50331648;    // [4096][768] attention outputs (pre out-proj)
static constexpr size_t OFF_WOK   = 62914560;    // [768][768]  Wk@Wout
static constexpr size_t OFF_WOV   = 65273856;    // [768][768]  Wv@Wout
static constexpr size_t OFF_BOKV  = 67633152;    // [1536]
static constexpr size_t OFF_OFLAG = 67639296;    // [4096] int, stride 32 ints (128B lines)
static constexpr size_t OFF_DONEV = 68163584;    // [4096] int, stride 32 ints
static constexpr size_t WS_NEEDED = 68687872;    // ~65.5 MiB  (< 82.8 MiB proven available)

__device__ __forceinline__ float dot4(float4 a, float4 b) {
  return fmaf(a.x, b.x, fmaf(a.y, b.y, fmaf(a.z, b.z, a.w * b.w)));
}

// ======= C[M x Ncols] = A[M x K] * B[Ncols x K]^T + bias[col]  (64x64 tile — proven) =======
__global__ __launch_bounds__(256) void gemm_nt_bias(
    const float* __restrict__ A, const float* __restrict__ B,
    const float* __restrict__ bias, float* __restrict__ C,
    int Kdim, int Ncols)
{
  __shared__ float As[16][68];
  __shared__ float Bs[16][68];
  const int t  = threadIdx.x;
  const int tm = t & 15, tn = t >> 4;
  const int row0 = blockIdx.y * 64;
  const int col0 = blockIdx.x * 64;
  const int lr = t >> 2, lk = (t & 3) << 2;
  float acc[4][4] = {};
  for (int k0 = 0; k0 < Kdim; k0 += 16) {
    float4 av = *(const float4*)(A + (size_t)(row0 + lr) * Kdim + k0 + lk);
    float4 bv = *(const float4*)(B + (size_t)(col0 + lr) * Kdim + k0 + lk);
    As[lk + 0][lr] = av.x; As[lk + 1][lr] = av.y; As[lk + 2][lr] = av.z; As[lk + 3][lr] = av.w;
    Bs[lk + 0][lr] = bv.x; Bs[lk + 1][lr] = bv.y; Bs[lk + 2][lr] = bv.z; Bs[lk + 3][lr] = bv.w;
    __syncthreads();
#pragma unroll
    for (int k = 0; k < 16; ++k) {
      float4 a4 = *(const float4*)&As[k][tm << 2];
      float4 b4 = *(const float4*)&Bs[k][tn << 2];
      float aa[4] = {a4.x, a4.y, a4.z, a4.w};
      float bb[4] = {b4.x, b4.y, b4.z, b4.w};
#pragma unroll
      for (int x = 0; x < 4; ++x)
#pragma unroll
        for (int y = 0; y < 4; ++y) acc[x][y] = fmaf(aa[x], bb[y], acc[x][y]);
    }
    __syncthreads();
  }
  float4 bi = *(const float4*)(bias + col0 + (tn << 2));
#pragma unroll
  for (int x = 0; x < 4; ++x) {
    float4 o = make_float4(acc[x][0] + bi.x, acc[x][1] + bi.y, acc[x][2] + bi.z, acc[x][3] + bi.w);
    *(float4*)(C + (size_t)(row0 + (tm << 2) + x) * Ncols + col0 + (tn << 2)) = o;
  }
}

// ============ C[M x Ncols] = A[M x K] * B[K x Ncols]  (64x64 tile — proven) ============
__global__ __launch_bounds__(256) void gemm_nn(
    const float* __restrict__ A, const float* __restrict__ B, float* __restrict__ C,
    int Kdim, int Ncols)
{
  __shared__ float As[16][68];
  __shared__ float Bs[16][68];
  const int t  = threadIdx.x;
  const int tm = t & 15, tn = t >> 4;
  const int row0 = blockIdx.y * 64;
  const int col0 = blockIdx.x * 64;
  const int lr = t >> 2, lk = (t & 3) << 2;
  const int ek = t >> 4, dc = (t & 15) << 2;
  float acc[4][4] = {};
  for (int k0 = 0; k0 < Kdim; k0 += 16) {
    float4 av = *(const float4*)(A + (size_t)(row0 + lr) * Kdim + k0 + lk);
    As[lk + 0][lr] = av.x; As[lk + 1][lr] = av.y; As[lk + 2][lr] = av.z; As[lk + 3][lr] = av.w;
    float4 bv = *(const float4*)(B + (size_t)(k0 + ek) * Ncols + col0 + dc);
    *(float4*)&Bs[ek][dc] = bv;
    __syncthreads();
#pragma unroll
    for (int k = 0; k < 16; ++k) {
      float4 a4 = *(const float4*)&As[k][tm << 2];
      float4 b4 = *(const float4*)&Bs[k][tn << 2];
      float aa[4] = {a4.x, a4.y, a4.z, a4.w};
      float bb[4] = {b4.x, b4.y, b4.z, b4.w};
#pragma unroll
      for (int x = 0; x < 4; ++x)
#pragma unroll
        for (int y = 0; y < 4; ++y) acc[x][y] = fmaf(aa[x], bb[y], acc[x][y]);
    }
    __syncthreads();
  }
#pragma unroll
  for (int x = 0; x < 4; ++x) {
    float4 o = make_float4(acc[x][0], acc[x][1], acc[x][2], acc[x][3]);
    *(float4*)(C + (size_t)(row0 + (tm << 2) + x) * Ncols + col0 + (tn << 2)) = o;
  }
}

// bokv[j] = Wk[j,:]·bout + bk[j];  bokv[768+j] = Wv[j,:]·bout + bv[j]
__global__ __launch_bounds__(256) void fuse_bias(
    const float* __restrict__ in_w, const float* __restrict__ in_b,
    const float* __restrict__ bout, float* __restrict__ bokv)
{
  int jj = blockIdx.x * 256 + threadIdx.x;
  if (jj >= 1536) return;
  const float* wrow = in_w + (size_t)(768 + jj) * 768;
  float s = 0.f;
  for (int e = 0; e < 768; e += 4) {
    float4 w4 = *(const float4*)(wrow + e);
    float4 b4 = *(const float4*)(bout + e);
    s += dot4(w4, b4);
  }
  bokv[jj] = s + in_b[768 + jj];
}

// ===================== persistent dataflow kernel: qt-transformed K-edge =====================
__global__ __launch_bounds__(256, 4) void multiattn_main(
    const int* __restrict__ nbr,
    const float* __restrict__ Call,
    float* __restrict__ Vnew, float* __restrict__ obuf,
    const float* __restrict__ Wok, const float* __restrict__ Wov,
    const float* __restrict__ bokv,
    int* __restrict__ oflag, int* __restrict__ doneV)
{
  const int w = blockIdx.x;
  const int t = threadIdx.x;

  if (w < NMVTOT) {
    // -------- V-army: 21 groups x 24 slices; 32 Wov rows per WG, 8 lanes per dot --------
    const int g = w / NSLICE_V;
    const int slice = w - g * NSLICE_V;
    __shared__ float o_lds[800];                 // 8 chunks of 96, stride 100
    const int gg = t >> 3, l = t & 7;
    const int row = slice * 32 + gg;             // 0..767
    const float* wrow = Wov + (size_t)row * 768 + l * 96;
    float4 wreg[24];
#pragma unroll
    for (int q = 0; q < 24; ++q) wreg[q] = *(const float4*)(wrow + 4 * q);
    const float biasv = bokv[768 + row];

    for (int i = g; i < N_USERS; i += NG_V) {
      if (t == 0) {
        const int* fp = oflag + ((size_t)i << 5);
        while (__hip_atomic_load(fp, __ATOMIC_RELAXED, __HIP_MEMORY_SCOPE_AGENT) < 1)
          __builtin_amdgcn_s_sleep(1);
        (void)__hip_atomic_load(fp, __ATOMIC_ACQUIRE, __HIP_MEMORY_SCOPE_AGENT);
      }
      __syncthreads();
      if (t < 192) {
        int d0 = t << 2;
        int ll = t / 24;
        int m  = d0 - ll * 96;
        *(float4*)&o_lds[ll * 100 + m] = *(const float4*)(obuf + (size_t)i * 768 + d0);
      }
      __syncthreads();
      float acc = 0.f;
      const float4* op = (const float4*)&o_lds[l * 100];
#pragma unroll
      for (int q = 0; q < 24; ++q) acc += dot4(wreg[q], op[q]);
      acc += __shfl_xor(acc, 1);
      acc += __shfl_xor(acc, 2);
      acc += __shfl_xor(acc, 4);
      if (l == 0) Vnew[(size_t)i * 768 + row] = acc + biasv;
      __syncthreads();
      if (t == 0)
        __hip_atomic_fetch_add(doneV + ((size_t)i << 5), 1,
                               __ATOMIC_RELEASE, __HIP_MEMORY_SCOPE_AGENT);
    }
  } else {
    // -------- attention: 128 static groups, one WG per step, all 4 heads --------
    const int a = w - NMVTOT;
    __shared__ float qt_lds[3072];               // qt_h = Wok_h^T q_h, 4 heads x 768
    __shared__ float qC[768];
    __shared__ int   idxb[2][KNB];
    __shared__ float sc_s[4][33];
    __shared__ float aw_s[4][33];
    __shared__ float qb_s[4];
    const int kp = t >> 3, l = t & 7;

    if (t < KNB) idxb[0][t] = nbr[(size_t)a * KNB + t];
    __syncthreads();

    for (int i = a; i < N_USERS; i += NG_A) {
      const int par = (i >> 7) & 1;              // stride 128 → flips each iteration

      // ---- stage q row
      if (t < 192) *(float4*)&qC[t << 2] = *(const float4*)(Call + (size_t)i * 2304 + (t << 2));
      __syncthreads();

      // ---- qt transform (no dependency — hides in pre-wait time):
      // thread owns 12 consecutive output dims of one head
      {
        const int h = t >> 6, d0 = (t & 63) * 12;
        float4 qa0 = {0,0,0,0}, qa1 = {0,0,0,0}, qa2 = {0,0,0,0};
        const float* wbase = Wok + (size_t)(h * 192) * 768 + d0;
        const float* qp = &qC[h * 192];
        for (int kk = 0; kk < 192; ++kk) {
          const float qv = qp[kk];
          const float* wr = wbase + (size_t)kk * 768;
          float4 w0 = *(const float4*)(wr);
          float4 w1 = *(const float4*)(wr + 4);
          float4 w2 = *(const float4*)(wr + 8);
          qa0.x = fmaf(qv, w0.x, qa0.x); qa0.y = fmaf(qv, w0.y, qa0.y);
          qa0.z = fmaf(qv, w0.z, qa0.z); qa0.w = fmaf(qv, w0.w, qa0.w);
          qa1.x = fmaf(qv, w1.x, qa1.x); qa1.y = fmaf(qv, w1.y, qa1.y);
          qa1.z = fmaf(qv, w1.z, qa1.z); qa1.w = fmaf(qv, w1.w, qa1.w);
          qa2.x = fmaf(qv, w2.x, qa2.x); qa2.y = fmaf(qv, w2.y, qa2.y);
          qa2.z = fmaf(qv, w2.z, qa2.z); qa2.w = fmaf(qv, w2.w, qa2.w);
        }
        *(float4*)&qt_lds[h * 768 + d0]     = qa0;
        *(float4*)&qt_lds[h * 768 + d0 + 4] = qa1;
        *(float4*)&qt_lds[h * 768 + d0 + 8] = qa2;
      }
      // qb_h = q_h · bokv_h (bias term of transformed scores)
      if (t < 32) {
        const int h = t >> 3, ll = t & 7;
        float s = 0.f;
        for (int kk = ll * 24; kk < ll * 24 + 24; ++kk)
          s = fmaf(qC[h * 192 + kk], bokv[h * 192 + kk], s);
        s += __shfl_xor(s, 1); s += __shfl_xor(s, 2); s += __shfl_xor(s, 4);
        if (ll == 0) qb_s[h] = s;
      }
      __syncthreads();

      // ---- K-side dependency: only o_r needed (single hop) — one lane per neighbor
      if (t < KNB) {
        const int r = idxb[par][t];
        if (r < i) {
          const int* fp = oflag + ((size_t)r << 5);
          while (__hip_atomic_load(fp, __ATOMIC_RELAXED, __HIP_MEMORY_SCOPE_AGENT) < 1)
            __builtin_amdgcn_s_sleep(1);
          (void)__hip_atomic_load(fp, __ATOMIC_ACQUIRE, __HIP_MEMORY_SCOPE_AGENT);
        }
      }
      __syncthreads();

      // prefetch next neighbor list (hide latency)
      int rn = 0;
      const bool pf = (t < KNB) && (i + NG_A < N_USERS);
      if (pf) rn = nbr[(size_t)(i + NG_A) * KNB + t];

      // ---- QK: 8 lanes per neighbor; chunks stay within one head (h = j/6)
      {
        const int r = idxb[par][kp];
        float acc0 = 0.f, acc1 = 0.f, acc2 = 0.f, acc3 = 0.f;
        if (r < i) {
          const float* ob = obuf + (size_t)r * 768;
#pragma unroll
          for (int j = 0; j < 24; ++j) {
            const int c4 = (j / 6) * 192 + (j % 6) * 32 + l * 4;
            float4 ov = *(const float4*)(ob + c4);
            acc0 += dot4(ov, *(const float4*)&qt_lds[c4]);
            acc1 += dot4(ov, *(const float4*)&qt_lds[768 + c4]);
            acc2 += dot4(ov, *(const float4*)&qt_lds[1536 + c4]);
            acc3 += dot4(ov, *(const float4*)&qt_lds[2304 + c4]);
          }
        } else {
          const float* kb = Call + (size_t)r * 2304 + 768;
#pragma unroll
          for (int j = 0; j < 24; ++j) {
            const int h = j / 6;
            const int c4 = h * 192 + (j % 6) * 32 + l * 4;
            float d = dot4(*(const float4*)(kb + c4), *(const float4*)&qC[c4]);
            if (h == 0) acc0 += d; else if (h == 1) acc1 += d;
            else if (h == 2) acc2 += d; else acc3 += d;
          }
        }
        acc0 += __shfl_xor(acc0, 1); acc0 += __shfl_xor(acc0, 2); acc0 += __shfl_xor(acc0, 4);
        acc1 += __shfl_xor(acc1, 1); acc1 += __shfl_xor(acc1, 2); acc1 += __shfl_xor(acc1, 4);
        acc2 += __shfl_xor(acc2, 1); acc2 += __shfl_xor(acc2, 2); acc2 += __shfl_xor(acc2, 4);
        acc3 += __shfl_xor(acc3, 1); acc3 += __shfl_xor(acc3, 2); acc3 += __shfl_xor(acc3, 4);
        if (l == 0) {
          const float bq = (r < i) ? 1.0f : 0.0f;
          const float scale = 0.07216878364870322f;   // 1/sqrt(192)
          sc_s[0][kp] = (acc0 + bq * qb_s[0]) * scale;
          sc_s[1][kp] = (acc1 + bq * qb_s[1]) * scale;
          sc_s[2][kp] = (acc2 + bq * qb_s[2]) * scale;
          sc_s[3][kp] = (acc3 + bq * qb_s[3]) * scale;
        }
      }
      __syncthreads();

      // ---- softmax: 128 lanes = 4 heads x 32 neighbors
      if (t < 128) {
        const int h = t >> 5, jj = t & 31;
        float s = sc_s[h][jj];
        float mx = s;
#pragma unroll
        for (int msk = 16; msk >= 1; msk >>= 1) mx = fmaxf(mx, __shfl_xor(mx, msk));
        float e = expf(s - mx);
        float sm = e;
#pragma unroll
        for (int msk = 16; msk >= 1; msk >>= 1) sm += __shfl_xor(sm, msk);
        aw_s[h][jj] = e / sm;
      }
      __syncthreads();
      if (pf) idxb[1 - par][t] = rn;

      // ---- V-side dependency (V-army overlapped with our QK+softmax)
      if (t < KNB) {
        const int r = idxb[par][t];
        if (r < i) {
          const int* fp = doneV + ((size_t)r << 5);
          while (__hip_atomic_load(fp, __ATOMIC_RELAXED, __HIP_MEMORY_SCOPE_AGENT) < NSLICE_V)
            __builtin_amdgcn_s_sleep(1);
          (void)__hip_atomic_load(fp, __ATOMIC_ACQUIRE, __HIP_MEMORY_SCOPE_AGENT);
        }
      }
      __syncthreads();

      // ---- AV: 192 lanes own 4 output dims, iterate neighbors
      if (t < 192) {
        const int d0 = t << 2;
        const int h  = t / 48;
        float4 o = make_float4(0.f, 0.f, 0.f, 0.f);
#pragma unroll 8
        for (int n = 0; n < KNB; ++n) {
          const int rr = idxb[par][n];
          const float av = aw_s[h][n];
          const float* vp = (rr < i) ? (Vnew + (size_t)rr * 768)
                                     : (Call + (size_t)rr * 2304 + 1536);
          float4 v = *(const float4*)(vp + d0);
          o.x = fmaf(av, v.x, o.x); o.y = fmaf(av, v.y, o.y);
          o.z = fmaf(av, v.z, o.z); o.w = fmaf(av, v.w, o.w);
        }
        *(float4*)(obuf + (size_t)i * 768 + d0) = o;
      }
      __syncthreads();
      if (t == 0)
        __hip_atomic_fetch_add(oflag + ((size_t)i << 5), 1,
                               __ATOMIC_RELEASE, __HIP_MEMORY_SCOPE_AGENT);
    }
  }
}

extern "C" void kernel_launch(void* const* d_in, const int* in_sizes, int n_in,
                              void* d_out, int out_size, void* d_ws, size_t ws_size,
                              hipStream_t stream)
{
  (void)in_sizes; (void)n_in; (void)out_size; (void)ws_size;
  const int*   nbr   = (const int*)d_in[0];
  const float* feat  = (const float*)d_in[1];
  const float* in_w  = (const float*)d_in[2];
  const float* in_b  = (const float*)d_in[3];
  const float* out_w = (const float*)d_in[4];
  const float* out_b = (const float*)d_in[5];
  float* outF = (float*)d_out;
  char*  ws   = (char*)d_ws;

  float* Call = (float*)(ws + OFF_CALL);
  float* Vnew = (float*)(ws + OFF_VNEW);
  float* obuf = (float*)(ws + OFF_OBUF);
  float* Wok  = (float*)(ws + OFF_WOK);
  float* Wov  = (float*)(ws + OFF_WOV);
  float* bokv = (float*)(ws + OFF_BOKV);
  int* oflag  = (int*)(ws + OFF_OFLAG);
  int* doneV  = (int*)(ws + OFF_DONEV);

  // zero flag region (ws is poisoned 0xAA before every call)
  hipMemsetAsync(ws + OFF_OFLAG, 0, WS_NEEDED - OFF_OFLAG, stream);

  // Qall | K0 | V0 = F0 @ [Wq;Wk;Wv]^T + b   -> Call [4096 x 2304]
  gemm_nt_bias<<<dim3(36, 64), 256, 0, stream>>>(feat, in_w, in_b, Call, 768, 2304);
  // Wok = Wk @ Wout, Wov = Wv @ Wout
  gemm_nn<<<dim3(12, 12), 256, 0, stream>>>(in_w + (size_t)768 * 768,  out_w, Wok, 768, 768);
  gemm_nn<<<dim3(12, 12), 256, 0, stream>>>(in_w + (size_t)1536 * 768, out_w, Wov, 768, 768);
  fuse_bias<<<6, 256, 0, stream>>>(in_w, in_b, out_b, bokv);

  multiattn_main<<<NWG, 256, 0, stream>>>(nbr, Call, Vnew, obuf,
      Wok, Wov, bokv, oflag, doneV);

  // tail: out = obuf @ Wout^T + bout  (fully parallel, off the critical path)
  gemm_nt_bias<<<dim3(12, 64), 256, 0, stream>>>(obuf, out_w, out_b, outF, 768, 768);
}